// Round 1
// baseline (408.001 us; speedup 1.0000x reference)
//
#include <hip/hip_runtime.h>
#include <hip/hip_bf16.h>
#include <stdint.h>

#define KTOT 8192
#define BM 32
#define BK 128

typedef __attribute__((ext_vector_type(8))) __bf16 bf16x8;
typedef __attribute__((ext_vector_type(4))) float f32x4;

__device__ __forceinline__ unsigned short f2bf(float f) {
  union { float f; unsigned int u; } a;
  a.f = f;
  unsigned int r = (a.u + 0x7fffu + ((a.u >> 16) & 1u)) >> 16;
  return (unsigned short)r;
}

// x [8192][64] f32  ->  xt [64][8192] bf16 (transposed)
__global__ __launch_bounds__(256) void xpose_f32_bf16(const float* __restrict__ x,
                                                      __hip_bfloat16* __restrict__ xt) {
  __shared__ unsigned short tile[64][72];
  const int r0 = blockIdx.x * 64;
  const int t = threadIdx.x;
  const int a = t >> 4;          // 0..15
  const int c4 = (t & 15) * 4;   // 0..60
#pragma unroll
  for (int rep = 0; rep < 4; ++rep) {
    int r = a + rep * 16;
    float4 v = *reinterpret_cast<const float4*>(x + (size_t)(r0 + r) * 64 + c4);
    tile[c4 + 0][r] = f2bf(v.x);
    tile[c4 + 1][r] = f2bf(v.y);
    tile[c4 + 2][r] = f2bf(v.z);
    tile[c4 + 3][r] = f2bf(v.w);
  }
  __syncthreads();
#pragma unroll
  for (int rep = 0; rep < 4; ++rep) {
    int j = a + rep * 16;
    uint2 v = *reinterpret_cast<const uint2*>(&tile[j][c4]);
    *reinterpret_cast<uint2*>((unsigned short*)xt + (size_t)j * KTOT + r0 + c4) = v;
  }
}

// C[8192][BN] = A(f32, [8192][8192]) @ B, with B given transposed bf16: BT[BN][8192].
// Epilogue: out writes (scaled, optional add of wa*add_ptr, optional accumulate)
// and optional bf16-transposed C store (raw, unscaled) for the next pass's RHS.
template <int BN>
__global__ __launch_bounds__(512, 1) void gemm_nt(
    const float* __restrict__ A, const __hip_bfloat16* __restrict__ BTv,
    float* __restrict__ out_lo, float* __restrict__ out_hi,
    const float* s_lo_ptr, const float* s_hi_ptr,
    const float* add_ptr, const float* add_s_ptr,
    __hip_bfloat16* bt_lo, __hip_bfloat16* bt_hi, int accum) {
  static_assert(BN == 64 || BN == 128, "");
  constexpr int SZ_A = BM * BK * 2;    // 8 KiB
  constexpr int SZ_B = BN * BK * 2;    // 32 / 16 KiB
  constexpr int NQ = BN / 32;          // global_load_lds issues per wave
  constexpr int CPW = BN / 4;          // cols per wave
  constexpr int NT = CPW / 16;         // 16x16 tiles per wave (N dir)
  constexpr int NIT = KTOT / BK;       // 64
  __shared__ unsigned char smem[2 * (SZ_A + SZ_B)];
  const unsigned short* BT = (const unsigned short*)BTv;

  const int t = threadIdx.x;
  const int l = t & 63;
  const int w = t >> 6;
  const int r0 = blockIdx.x * BM;

  // ---- A staging: 32x128 f32 tile, 2 float4 per thread, reg->bf16->LDS ----
  int goff_a[2], loff_a[2];
#pragma unroll
  for (int r = 0; r < 2; ++r) {
    int idx = t + r * 512;
    int m = idx >> 5, c4 = idx & 31;               // row 0..31, float4-col 0..31
    goff_a[r] = (r0 + m) * KTOT + c4 * 4;
    loff_a[r] = m * 256 + ((c4 * 8) ^ ((m & 7) << 4));  // XOR-swizzled byte off
  }

  // ---- B staging via global_load_lds (linear LDS dest, pre-swizzled source) ----
  int b_src_off[NQ];
  int b_lds_off[NQ];
#pragma unroll
  for (int q = 0; q < NQ; ++q) {
    int j = w + q * 8;            // 1KiB chunk id = 4 rows of 256B
    int n = 4 * j + (l >> 4);     // BT row this lane fetches for
    int c = l & 15;               // 16B chunk within row
    b_src_off[q] = n * KTOT + 8 * (c ^ (n & 7));   // element offset (sans k0)
    b_lds_off[q] = j * 1024;                        // wave-uniform LDS base
  }

  const int wm = w >> 2;       // 0..1
  const int wn = w & 3;        // 0..3
  const int lr = l & 15;
  const int g = l >> 4;
  const int arow = wm * 16 + lr;
  const int asw = (arow & 7) << 4;

  f32x4 acc[NT];
  const f32x4 fzero = {0.f, 0.f, 0.f, 0.f};
#pragma unroll
  for (int nt = 0; nt < NT; ++nt) acc[nt] = fzero;

  float4 av[2];

  auto stage_B = [&](int bufsel, int k0) {
#pragma unroll
    for (int q = 0; q < NQ; ++q) {
      const unsigned short* src = BT + b_src_off[q] + k0;
      unsigned char* dst = &smem[(bufsel ? (2 * SZ_A + SZ_B) : SZ_A) + b_lds_off[q]];
      __builtin_amdgcn_global_load_lds(
          (const __attribute__((address_space(1))) unsigned int*)src,
          (__attribute__((address_space(3))) unsigned int*)dst, 16, 0, 0);
    }
  };
  auto load_A = [&](int k0) {
#pragma unroll
    for (int r = 0; r < 2; ++r)
      av[r] = *reinterpret_cast<const float4*>(A + goff_a[r] + k0);
  };
  auto write_A = [&](int bufsel) {
    unsigned char* ab = &smem[bufsel ? (SZ_A + SZ_B) : 0];
#pragma unroll
    for (int r = 0; r < 2; ++r) {
      union { unsigned short h[4]; uint2 v; } pk;
      pk.h[0] = f2bf(av[r].x);
      pk.h[1] = f2bf(av[r].y);
      pk.h[2] = f2bf(av[r].z);
      pk.h[3] = f2bf(av[r].w);
      *reinterpret_cast<uint2*>(ab + loff_a[r]) = pk.v;
    }
  };
  auto compute = [&](int bufsel) {
    const unsigned char* ab = &smem[bufsel ? (SZ_A + SZ_B) : 0];
    const unsigned char* bb = &smem[bufsel ? (2 * SZ_A + SZ_B) : SZ_A];
#pragma unroll
    for (int ks = 0; ks < BK / 32; ++ks) {
      bf16x8 af = *reinterpret_cast<const bf16x8*>(
          ab + arow * 256 + ((ks * 64 + g * 16) ^ asw));
#pragma unroll
      for (int nt = 0; nt < NT; ++nt) {
        int n = wn * CPW + nt * 16 + lr;
        bf16x8 bfg = *reinterpret_cast<const bf16x8*>(
            bb + n * 256 + ((ks * 64 + g * 16) ^ ((n & 7) << 4)));
        acc[nt] = __builtin_amdgcn_mfma_f32_16x16x32_bf16(af, bfg, acc[nt], 0, 0, 0);
      }
    }
  };

  // prologue
  stage_B(0, 0);
  load_A(0);
  asm volatile("s_waitcnt vmcnt(0)" ::: "memory");
  write_A(0);
  __syncthreads();

  int buf = 0;
  for (int it = 0; it < NIT; ++it) {
    if (it + 1 < NIT) {
      stage_B(buf ^ 1, (it + 1) * BK);   // async into other buffer
      load_A((it + 1) * BK);             // A fp32 into regs
    }
    compute(buf);
    if (it + 1 < NIT) {
      asm volatile("s_waitcnt vmcnt(0)" ::: "memory");
      write_A(buf ^ 1);
    }
    __syncthreads();
    buf ^= 1;
  }

  // ---- epilogue ----
  const float s_lo = s_lo_ptr ? *s_lo_ptr : 0.f;
  const float s_hi = s_hi_ptr ? *s_hi_ptr : 0.f;
  const float was = add_s_ptr ? *add_s_ptr : 0.f;
  const int g4 = 4 * g;
  const int rbase = r0 + wm * 16 + g4;
#pragma unroll
  for (int nt = 0; nt < NT; ++nt) {
    int col = wn * CPW + nt * 16 + lr;                 // 0..BN-1
    bool hi = (BN == 128) && (col >= 64);
    int col64 = hi ? (col - 64) : col;
    __hip_bfloat16* bt = hi ? bt_hi : bt_lo;
    if (bt) {  // store raw C transposed as bf16: bt[col64][r]
      union { unsigned short h[4]; uint2 v; } pk;
#pragma unroll
      for (int i = 0; i < 4; ++i) pk.h[i] = f2bf(acc[nt][i]);
      *reinterpret_cast<uint2*>((unsigned short*)bt + (size_t)col64 * KTOT + rbase) = pk.v;
    }
    float* op = hi ? out_hi : out_lo;
    if (op) {
      float s = hi ? s_hi : s_lo;
#pragma unroll
      for (int i = 0; i < 4; ++i) {
        int r = rbase + i;
        float v = s * acc[nt][i];
        if (add_ptr) v = fmaf(was, add_ptr[(size_t)r * 64 + col64], v);
        if (accum) v += op[(size_t)r * 128 + col64];
        op[(size_t)r * 128 + col64] = v;
      }
    }
  }
}

extern "C" void kernel_launch(void* const* d_in, const int* in_sizes, int n_in,
                              void* d_out, int out_size, void* d_ws, size_t ws_size,
                              hipStream_t stream) {
  const float* A_p = (const float*)d_in[0];
  const float* A_n = (const float*)d_in[1];
  const float* x_p = (const float*)d_in[2];
  const float* x_n = (const float*)d_in[3];
  const float* w_p = (const float*)d_in[4];  // [3]
  const float* w_n = (const float*)d_in[5];  // [3]
  float* out = (float*)d_out;                // [8192][128]

  // workspace: 5 MiB of bf16 transposed RHS panels
  __hip_bfloat16* B1T = (__hip_bfloat16*)d_ws;         // [128][8192]: rows 0-63 x_p^T, 64-127 x_n^T
  __hip_bfloat16* B2T = B1T + (size_t)128 * KTOT;      // [128][8192]: rows 0-63 P1^T, 64-127 T1^T
  __hip_bfloat16* B3T = B2T + (size_t)128 * KTOT;      // [64][8192]:  Y1^T

  xpose_f32_bf16<<<128, 256, 0, stream>>>(x_p, B1T);
  xpose_f32_bf16<<<128, 256, 0, stream>>>(x_n, B1T + (size_t)64 * KTOT);

  // GEMM1: [P1|Y1] = A_p @ [x_p|x_n]; out[:,0:64] = wp0*x_p + wp1*P1; emit P1^T, Y1^T
  gemm_nt<128><<<256, 512, 0, stream>>>(A_p, B1T, out, nullptr, w_p + 1, nullptr,
                                        x_p, w_p + 0, B2T, B3T, 0);
  // GEMM2: T1 = A_n @ x_n; out[:,64:128] = wn0*T1; emit T1^T
  gemm_nt<64><<<256, 512, 0, stream>>>(A_n, B1T + (size_t)64 * KTOT, out + 64, nullptr,
                                       w_n + 0, nullptr, nullptr, nullptr,
                                       B2T + (size_t)64 * KTOT, nullptr, 0);
  // GEMM3: [P2|T2] = A_p @ [P1|T1]; out[:,0:64] += wp2*P2; out[:,64:128] += wn1*T2
  gemm_nt<128><<<256, 512, 0, stream>>>(A_p, B2T, out, out + 64, w_p + 2, w_n + 1,
                                        nullptr, nullptr, nullptr, nullptr, 1);
  // GEMM4: T3 = A_n @ Y1; out[:,64:128] += wn2*T3
  gemm_nt<64><<<256, 512, 0, stream>>>(A_n, B3T, out + 64, nullptr, w_n + 2, nullptr,
                                       nullptr, nullptr, nullptr, nullptr, 1);
}